// Round 1
// 229.720 us; speedup vs baseline: 1.2457x; 1.2457x over previous
//
#include <hip/hip_runtime.h>
#include <math.h>

#define L 2048
#define B 8
#define D 1024
#define ND 16
#define BD (B*D)

__device__ __forceinline__ float sigmoid_precise(float v) {
    return 1.0f / (1.0f + expf(-v));
}

// Per-mode decay q[16] for row `row` (row-major params: [2D][ND]).
__device__ __forceinline__ void load_q(const float* __restrict__ damp,
                                       const float* __restrict__ decay,
                                       int row, float* q) {
#pragma unroll
    for (int mg = 0; mg < 4; ++mg) {
        const float4 dp = reinterpret_cast<const float4*>(damp)[row * 4 + mg];
        const float4 dc = reinterpret_cast<const float4*>(decay)[row * 4 + mg];
        q[4*mg+0] = 1.f - sigmoid_precise(dp.x) * sigmoid_precise(dc.x);
        q[4*mg+1] = 1.f - sigmoid_precise(dp.y) * sigmoid_precise(dc.y);
        q[4*mg+2] = 1.f - sigmoid_precise(dp.z) * sigmoid_precise(dc.z);
        q[4*mg+3] = 1.f - sigmoid_precise(dp.w) * sigmoid_precise(dc.w);
    }
}

// Per-mode decay q[16] and output coefficient c[16] (= p * ema * proj * 1/sqrt(ND)).
__device__ __forceinline__ void load_qc(const float* __restrict__ damp,
                                        const float* __restrict__ decay,
                                        const float* __restrict__ ema,
                                        const float* __restrict__ proj,
                                        int row, float* q, float* c) {
#pragma unroll
    for (int mg = 0; mg < 4; ++mg) {
        const float4 dp = reinterpret_cast<const float4*>(damp)[row * 4 + mg];
        const float4 dc = reinterpret_cast<const float4*>(decay)[row * 4 + mg];
        const float4 em = reinterpret_cast<const float4*>(ema)[row * 4 + mg];
        const float4 pj = reinterpret_cast<const float4*>(proj)[row * 4 + mg];
        const float p0 = sigmoid_precise(dp.x), p1 = sigmoid_precise(dp.y),
                    p2 = sigmoid_precise(dp.z), p3 = sigmoid_precise(dp.w);
        q[4*mg+0] = 1.f - p0 * sigmoid_precise(dc.x);
        q[4*mg+1] = 1.f - p1 * sigmoid_precise(dc.y);
        q[4*mg+2] = 1.f - p2 * sigmoid_precise(dc.z);
        q[4*mg+3] = 1.f - p3 * sigmoid_precise(dc.w);
        c[4*mg+0] = p0 * em.x * pj.x * 0.25f;
        c[4*mg+1] = p1 * em.y * pj.y * 0.25f;
        c[4*mg+2] = p2 * em.z * pj.z * 0.25f;
        c[4*mg+3] = p3 * em.w * pj.w * 0.25f;
    }
}

// ---------------- Phase A: per-chunk local states (both directions) ----------
// Lane = one channel d; all ND modes in registers. Wave = 64 consecutive d
// of one (b, chunk) -> coalesced 256B x loads, wave-uniform mask loads.
template<int CK>
__global__ __launch_bounds__(64) void ema_summary_kernel(
    const float* __restrict__ x, const float* __restrict__ damp,
    const float* __restrict__ decay, const int* __restrict__ mask,
    float* __restrict__ fwdS, float* __restrict__ bwdS)
{
    constexpr int NC = L / CK;
    const int lane = threadIdx.x;
    const int d  = blockIdx.x * 64 + lane;
    const int b  = blockIdx.y;
    const int ch = blockIdx.z;
    const int j0 = ch * CK;

    const float* xp = x + (size_t)j0 * BD + (size_t)b * D + d;
    const int*   mp = mask + (size_t)b * L + j0;

    float q[ND], st[ND];

    // ---- forward direction (rows [0,D)): ascending scan ----
    load_q(damp, decay, d, q);
#pragma unroll
    for (int k = 0; k < ND; ++k) st[k] = 0.f;
    for (int u = 0; u < CK; u += 4) {
        const int4 m4 = *reinterpret_cast<const int4*>(mp + u);
        float xv[4];
#pragma unroll
        for (int v = 0; v < 4; ++v) xv[v] = xp[(size_t)(u + v) * BD];
        const float xm[4] = { xv[0] * (float)m4.x, xv[1] * (float)m4.y,
                              xv[2] * (float)m4.z, xv[3] * (float)m4.w };
#pragma unroll
        for (int v = 0; v < 4; ++v)
#pragma unroll
            for (int k = 0; k < ND; ++k) st[k] = fmaf(q[k], st[k], xm[v]);
    }
    {
        float4* s4 = reinterpret_cast<float4*>(fwdS) + ((size_t)(b * NC + ch) * D + d) * 4;
#pragma unroll
        for (int mg = 0; mg < 4; ++mg)
            s4[mg] = make_float4(st[4*mg+0], st[4*mg+1], st[4*mg+2], st[4*mg+3]);
    }

    // ---- backward direction (rows [D,2D)): descending scan ----
    load_q(damp, decay, d + D, q);
#pragma unroll
    for (int k = 0; k < ND; ++k) st[k] = 0.f;
    for (int u = CK - 4; u >= 0; u -= 4) {
        const int4 m4 = *reinterpret_cast<const int4*>(mp + u);
        float xv[4];
#pragma unroll
        for (int v = 0; v < 4; ++v) xv[v] = xp[(size_t)(u + v) * BD];
        const float xm[4] = { xv[0] * (float)m4.x, xv[1] * (float)m4.y,
                              xv[2] * (float)m4.z, xv[3] * (float)m4.w };
#pragma unroll
        for (int v = 3; v >= 0; --v)
#pragma unroll
            for (int k = 0; k < ND; ++k) st[k] = fmaf(q[k], st[k], xm[v]);
    }
    {
        float4* s4 = reinterpret_cast<float4*>(bwdS) + ((size_t)(b * NC + ch) * D + d) * 4;
#pragma unroll
        for (int mg = 0; mg < 4; ++mg)
            s4[mg] = make_float4(st[4*mg+0], st[4*mg+1], st[4*mg+2], st[4*mg+3]);
    }
}

// ---------------- Phase B: prefix across chunks (in-place -> entry states) ---
// One thread per (b, d, mode): B*D*ND = 131072 threads (8 waves/CU).
// All NC chunk-loads issued before the serial fma chain (latency hiding).
template<int CK>
__global__ __launch_bounds__(256) void ema_prefix_kernel(
    const float* __restrict__ damp, const float* __restrict__ decay,
    float* __restrict__ fwdS, float* __restrict__ bwdS)
{
    constexpr int NC = L / CK;
    constexpr int LOG2CK = (CK == 64) ? 6 : 7;
    const int tid = blockIdx.x * 256 + threadIdx.x;
    const int m = tid & (ND - 1);
    const int d = (tid >> 4) & (D - 1);
    const int b = tid >> 14;
    const size_t CS = (size_t)D * ND;   // stride between chunks

    // forward chain (modes of row d)
    {
        const int idx = d * ND + m;
        float qp = 1.f - sigmoid_precise(damp[idx]) * sigmoid_precise(decay[idx]);
#pragma unroll
        for (int s = 0; s < LOG2CK; ++s) qp *= qp;     // q^CK
        float* base = fwdS + (size_t)b * NC * CS + (size_t)d * ND + m;
        float Ebuf[NC];
#pragma unroll
        for (int i = 0; i < NC; ++i) Ebuf[i] = base[(size_t)i * CS];
        float F = 0.f;
#pragma unroll
        for (int i = 0; i < NC; ++i) {
            base[(size_t)i * CS] = F;                  // entry state for chunk i
            F = fmaf(qp, F, Ebuf[i]);
        }
    }
    // backward chain (modes of row d+D)
    {
        const int idx = (d + D) * ND + m;
        float qp = 1.f - sigmoid_precise(damp[idx]) * sigmoid_precise(decay[idx]);
#pragma unroll
        for (int s = 0; s < LOG2CK; ++s) qp *= qp;
        float* base = bwdS + (size_t)b * NC * CS + (size_t)d * ND + m;
        float Ebuf[NC];
#pragma unroll
        for (int i = 0; i < NC; ++i) Ebuf[i] = base[(size_t)i * CS];
        float G = 0.f;
#pragma unroll
        for (int i = NC - 1; i >= 0; --i) {
            base[(size_t)i * CS] = G;                  // entry state for chunk i
            G = fmaf(qp, G, Ebuf[i]);
        }
    }
}

// ---------------- Phase C: apply (both directions + residual + silu) ---------
// Lane = one channel, all ND modes in-lane: no shfl reduction, no redundant
// loads, all 64 lanes store (coalesced). LDS scratch is per-lane only ->
// no __syncthreads anywhere.
template<int CK>
__global__ __launch_bounds__(64) void ema_apply_kernel(
    const float* __restrict__ x, const float* __restrict__ damp,
    const float* __restrict__ decay, const float* __restrict__ ema,
    const float* __restrict__ proj, const float* __restrict__ rw,
    const int* __restrict__ mask,
    const float* __restrict__ fwdS, const float* __restrict__ bwdS,
    float* __restrict__ out)
{
    constexpr int NC = L / CK;
    __shared__ float tile[CK * 64];    // per-lane column: fwd contribution + residual

    const int lane = threadIdx.x;
    const int d  = blockIdx.x * 64 + lane;
    const int b  = blockIdx.y;
    const int ch = blockIdx.z;
    const int j0 = ch * CK;

    const float* xp = x   + (size_t)j0 * BD + (size_t)b * D + d;
    float*       op = out + (size_t)j0 * BD + (size_t)b * D + d;
    const int*   mp = mask + (size_t)b * L + j0;
    const float  w  = rw[d];

    float q[ND], c[ND], st[ND];

    // ---- forward (causal) sweep: residual + causal part into LDS column ----
    load_qc(damp, decay, ema, proj, d, q, c);
    {
        const float4* s4 = reinterpret_cast<const float4*>(fwdS) + ((size_t)(b * NC + ch) * D + d) * 4;
#pragma unroll
        for (int mg = 0; mg < 4; ++mg) {
            const float4 v = s4[mg];
            st[4*mg+0] = v.x; st[4*mg+1] = v.y; st[4*mg+2] = v.z; st[4*mg+3] = v.w;
        }
    }
    for (int u = 0; u < CK; u += 4) {
        const int4 m4 = *reinterpret_cast<const int4*>(mp + u);
        float xv[4];
#pragma unroll
        for (int v = 0; v < 4; ++v) xv[v] = xp[(size_t)(u + v) * BD];
        const float xm[4] = { xv[0] * (float)m4.x, xv[1] * (float)m4.y,
                              xv[2] * (float)m4.z, xv[3] * (float)m4.w };
#pragma unroll
        for (int v = 0; v < 4; ++v) {
#pragma unroll
            for (int k = 0; k < ND; ++k) st[k] = fmaf(q[k], st[k], xm[v]);
            float a0 = c[0] * st[0], a1 = c[1] * st[1],
                  a2 = c[2] * st[2], a3 = c[3] * st[3];
#pragma unroll
            for (int k = 4; k < ND; k += 4) {
                a0 = fmaf(c[k+0], st[k+0], a0);
                a1 = fmaf(c[k+1], st[k+1], a1);
                a2 = fmaf(c[k+2], st[k+2], a2);
                a3 = fmaf(c[k+3], st[k+3], a3);
            }
            tile[(u + v) * 64 + lane] = fmaf(xv[v], w, (a0 + a1) + (a2 + a3));
        }
    }

    // ---- backward (anti-causal) sweep: combine + silu + coalesced store ----
    load_qc(damp, decay, ema, proj, d + D, q, c);
    {
        const float4* s4 = reinterpret_cast<const float4*>(bwdS) + ((size_t)(b * NC + ch) * D + d) * 4;
#pragma unroll
        for (int mg = 0; mg < 4; ++mg) {
            const float4 v = s4[mg];
            st[4*mg+0] = v.x; st[4*mg+1] = v.y; st[4*mg+2] = v.z; st[4*mg+3] = v.w;
        }
    }
    for (int u = CK - 4; u >= 0; u -= 4) {
        const int4 m4 = *reinterpret_cast<const int4*>(mp + u);
        float xv[4];
#pragma unroll
        for (int v = 0; v < 4; ++v) xv[v] = xp[(size_t)(u + v) * BD];
        const float xm[4] = { xv[0] * (float)m4.x, xv[1] * (float)m4.y,
                              xv[2] * (float)m4.z, xv[3] * (float)m4.w };
#pragma unroll
        for (int v = 3; v >= 0; --v) {
#pragma unroll
            for (int k = 0; k < ND; ++k) st[k] = fmaf(q[k], st[k], xm[v]);
            float a0 = c[0] * st[0], a1 = c[1] * st[1],
                  a2 = c[2] * st[2], a3 = c[3] * st[3];
#pragma unroll
            for (int k = 4; k < ND; k += 4) {
                a0 = fmaf(c[k+0], st[k+0], a0);
                a1 = fmaf(c[k+1], st[k+1], a1);
                a2 = fmaf(c[k+2], st[k+2], a2);
                a3 = fmaf(c[k+3], st[k+3], a3);
            }
            const float val = tile[(u + v) * 64 + lane] + ((a0 + a1) + (a2 + a3));
            op[(size_t)(u + v) * BD] = val / (1.0f + expf(-val));
        }
    }
}

// ---------------- Fallback: validated single-pass scans ----------------------
template<int DIR>
__device__ __forceinline__ void ema_scan_body(
    const float* __restrict__ x, const float* __restrict__ damp,
    const float* __restrict__ decay, const float* __restrict__ ema,
    const float* __restrict__ proj, const float* __restrict__ rw,
    const int* __restrict__ mask, float* __restrict__ out)
{
    const int t  = threadIdx.x;
    const int ng = t & 3;
    const int dl = t >> 2;
    const int d  = blockIdx.x * 16 + dl;
    const int b  = blockIdx.y;
    const int row = (DIR == 0) ? d : (d + D);

    float q[4], c[4];
#pragma unroll
    for (int k = 0; k < 4; ++k) {
        const int idx = row * ND + ng * 4 + k;
        const float p  = sigmoid_precise(damp[idx]);
        const float sd = sigmoid_precise(decay[idx]);
        q[k] = 1.0f - p * sd;
        c[k] = p * ema[idx] * proj[idx] * 0.25f;
    }
    const float w = rw[d];
    const float* xp = x + (size_t)b * D + d;
    float*       op = out + (size_t)b * D + d;
    const int*   mp = mask + (size_t)b * L;
    float s0 = 0.f, s1 = 0.f, s2 = 0.f, s3 = 0.f;

    for (int jj = 0; jj < L; jj += 4) {
        float xv[4], mf[4];
#pragma unroll
        for (int u = 0; u < 4; ++u) {
            const int j = (DIR == 0) ? (jj + u) : (L - 1 - (jj + u));
            xv[u] = xp[(size_t)j * BD];
            mf[u] = (float)mp[j];
        }
        float acc[4];
#pragma unroll
        for (int u = 0; u < 4; ++u) {
            const float xm = xv[u] * mf[u];
            s0 = fmaf(q[0], s0, xm);
            s1 = fmaf(q[1], s1, xm);
            s2 = fmaf(q[2], s2, xm);
            s3 = fmaf(q[3], s3, xm);
            acc[u] = fmaf(c[1], s1, c[0] * s0) + fmaf(c[3], s3, c[2] * s2);
        }
#pragma unroll
        for (int u = 0; u < 4; ++u) acc[u] += __shfl_xor(acc[u], 1);
#pragma unroll
        for (int u = 0; u < 4; ++u) acc[u] += __shfl_xor(acc[u], 2);
        if (ng == 0) {
#pragma unroll
            for (int u = 0; u < 4; ++u) {
                const int j = (DIR == 0) ? (jj + u) : (L - 1 - (jj + u));
                const size_t oi = (size_t)j * BD;
                if (DIR == 0) op[oi] = fmaf(xv[u], w, acc[u]);
                else { const float v = op[oi] + acc[u]; op[oi] = v / (1.0f + expf(-v)); }
            }
        }
    }
}

__global__ __launch_bounds__(64) void ema_fwd_kernel(
    const float* __restrict__ x, const float* __restrict__ damp,
    const float* __restrict__ decay, const float* __restrict__ ema,
    const float* __restrict__ proj, const float* __restrict__ rw,
    const int* __restrict__ mask, float* __restrict__ out)
{ ema_scan_body<0>(x, damp, decay, ema, proj, rw, mask, out); }

__global__ __launch_bounds__(64) void ema_bwd_kernel(
    const float* __restrict__ x, const float* __restrict__ damp,
    const float* __restrict__ decay, const float* __restrict__ ema,
    const float* __restrict__ proj, const float* __restrict__ rw,
    const int* __restrict__ mask, float* __restrict__ out)
{ ema_scan_body<1>(x, damp, decay, ema, proj, rw, mask, out); }

// ---------------- driver -----------------------------------------------------
template<int CK>
static void launch_chunked(const float* x, const float* damp, const float* decay,
                           const float* ema, const float* proj, const float* rw,
                           const int* mask, float* out, float* ws, hipStream_t stream) {
    constexpr int NC = L / CK;
    float* fwdS = ws;
    float* bwdS = fwdS + (size_t)B * NC * D * ND;
    dim3 blk(64);
    dim3 g(D / 64, B, NC);
    ema_summary_kernel<CK><<<g, blk, 0, stream>>>(x, damp, decay, mask, fwdS, bwdS);
    ema_prefix_kernel<CK><<<dim3((B * D * ND) / 256), dim3(256), 0, stream>>>(damp, decay, fwdS, bwdS);
    ema_apply_kernel<CK><<<g, blk, 0, stream>>>(x, damp, decay, ema, proj, rw, mask,
                                                fwdS, bwdS, out);
}

extern "C" void kernel_launch(void* const* d_in, const int* in_sizes, int n_in,
                              void* d_out, int out_size, void* d_ws, size_t ws_size,
                              hipStream_t stream) {
    (void)in_sizes; (void)n_in; (void)out_size;
    const float* x     = (const float*)d_in[0];
    const float* damp  = (const float*)d_in[1];
    const float* decay = (const float*)d_in[2];
    const float* ema   = (const float*)d_in[3];
    const float* proj  = (const float*)d_in[4];
    const float* rw    = (const float*)d_in[5];
    const int*   mask  = (const int*)d_in[6];
    float* out = (float*)d_out;

    const size_t need64  = (size_t)2 * B * (L / 64)  * D * ND * sizeof(float);  // 33.6 MB
    const size_t need128 = (size_t)2 * B * (L / 128) * D * ND * sizeof(float);  // 16.8 MB

    if (ws_size >= need64) {
        launch_chunked<64>(x, damp, decay, ema, proj, rw, mask, out, (float*)d_ws, stream);
    } else if (ws_size >= need128) {
        launch_chunked<128>(x, damp, decay, ema, proj, rw, mask, out, (float*)d_ws, stream);
    } else {
        dim3 grid(D / 16, B);
        dim3 block(64);
        ema_fwd_kernel<<<grid, block, 0, stream>>>(x, damp, decay, ema, proj, rw, mask, out);
        ema_bwd_kernel<<<grid, block, 0, stream>>>(x, damp, decay, ema, proj, rw, mask, out);
    }
}

// Round 2
// 211.534 us; speedup vs baseline: 1.3528x; 1.0860x over previous
//
#include <hip/hip_runtime.h>
#include <math.h>

#define L 2048
#define B 8
#define D 1024
#define ND 16
#define BD (B*D)

__device__ __forceinline__ float sigmoid_precise(float v) {
    return 1.0f / (1.0f + expf(-v));
}

// Per-mode decay q[16] for row `row` (row-major params: [2D][ND]).
__device__ __forceinline__ void load_q(const float* __restrict__ damp,
                                       const float* __restrict__ decay,
                                       int row, float* q) {
#pragma unroll
    for (int mg = 0; mg < 4; ++mg) {
        const float4 dp = reinterpret_cast<const float4*>(damp)[row * 4 + mg];
        const float4 dc = reinterpret_cast<const float4*>(decay)[row * 4 + mg];
        q[4*mg+0] = 1.f - sigmoid_precise(dp.x) * sigmoid_precise(dc.x);
        q[4*mg+1] = 1.f - sigmoid_precise(dp.y) * sigmoid_precise(dc.y);
        q[4*mg+2] = 1.f - sigmoid_precise(dp.z) * sigmoid_precise(dc.z);
        q[4*mg+3] = 1.f - sigmoid_precise(dp.w) * sigmoid_precise(dc.w);
    }
}

// Per-mode decay q[16] and output coefficient c[16] (= p * ema * proj / sqrt(ND)).
__device__ __forceinline__ void load_qc(const float* __restrict__ damp,
                                        const float* __restrict__ decay,
                                        const float* __restrict__ ema,
                                        const float* __restrict__ proj,
                                        int row, float* q, float* c) {
#pragma unroll
    for (int mg = 0; mg < 4; ++mg) {
        const float4 dp = reinterpret_cast<const float4*>(damp)[row * 4 + mg];
        const float4 dc = reinterpret_cast<const float4*>(decay)[row * 4 + mg];
        const float4 em = reinterpret_cast<const float4*>(ema)[row * 4 + mg];
        const float4 pj = reinterpret_cast<const float4*>(proj)[row * 4 + mg];
        const float p0 = sigmoid_precise(dp.x), p1 = sigmoid_precise(dp.y),
                    p2 = sigmoid_precise(dp.z), p3 = sigmoid_precise(dp.w);
        q[4*mg+0] = 1.f - p0 * sigmoid_precise(dc.x);
        q[4*mg+1] = 1.f - p1 * sigmoid_precise(dc.y);
        q[4*mg+2] = 1.f - p2 * sigmoid_precise(dc.z);
        q[4*mg+3] = 1.f - p3 * sigmoid_precise(dc.w);
        c[4*mg+0] = p0 * em.x * pj.x * 0.25f;
        c[4*mg+1] = p1 * em.y * pj.y * 0.25f;
        c[4*mg+2] = p2 * em.z * pj.z * 0.25f;
        c[4*mg+3] = p3 * em.w * pj.w * 0.25f;
    }
}

// ---------------- Phase A: per-chunk local states (both directions) ----------
// Lane = one channel d. Whole chunk of x prefetched to registers (latency paid
// once, 64 outstanding loads), then fwd+bwd scans run MERGED in one loop from
// registers (32 independent fma chains of ILP). Mask loads are wave-uniform
// scalar loads.
template<int CK>
__global__ __launch_bounds__(64, 2) void ema_summary_kernel(
    const float* __restrict__ x, const float* __restrict__ damp,
    const float* __restrict__ decay, const int* __restrict__ mask,
    float* __restrict__ fwdS, float* __restrict__ bwdS)
{
    constexpr int NC = L / CK;
    const int lane = threadIdx.x;
    const int d  = blockIdx.x * 64 + lane;
    const int b  = blockIdx.y;
    const int ch = blockIdx.z;
    const int j0 = ch * CK;

    const float* xp = x + (size_t)j0 * BD + (size_t)b * D + d;
    const int*   mp = mask + (size_t)b * L + j0;   // wave-uniform

    float xm[CK];
#pragma unroll
    for (int u = 0; u < CK; ++u) xm[u] = xp[(size_t)u * BD];
#pragma unroll
    for (int u = 0; u < CK; ++u) xm[u] *= (float)mp[u];

    float qf[ND], qb[ND], sf[ND], sb[ND];
    load_q(damp, decay, d,     qf);
    load_q(damp, decay, d + D, qb);
#pragma unroll
    for (int k = 0; k < ND; ++k) { sf[k] = 0.f; sb[k] = 0.f; }

#pragma unroll
    for (int u = 0; u < CK; ++u) {
        const float xf = xm[u];
        const float xb = xm[CK - 1 - u];
#pragma unroll
        for (int k = 0; k < ND; ++k) {
            sf[k] = fmaf(qf[k], sf[k], xf);
            sb[k] = fmaf(qb[k], sb[k], xb);
        }
    }

    {
        float4* s4 = reinterpret_cast<float4*>(fwdS) + ((size_t)(b * NC + ch) * D + d) * 4;
#pragma unroll
        for (int mg = 0; mg < 4; ++mg)
            s4[mg] = make_float4(sf[4*mg+0], sf[4*mg+1], sf[4*mg+2], sf[4*mg+3]);
    }
    {
        float4* s4 = reinterpret_cast<float4*>(bwdS) + ((size_t)(b * NC + ch) * D + d) * 4;
#pragma unroll
        for (int mg = 0; mg < 4; ++mg)
            s4[mg] = make_float4(sb[4*mg+0], sb[4*mg+1], sb[4*mg+2], sb[4*mg+3]);
    }
}

// ---------------- Phase B: prefix across chunks (in-place -> entry states) ---
// One thread per (b, d, mode). All chunk values prefetched, then the two
// serial fma chains (fwd + bwd) interleaved for 2x chain ILP.
template<int CK>
__global__ __launch_bounds__(256) void ema_prefix_kernel(
    const float* __restrict__ damp, const float* __restrict__ decay,
    float* __restrict__ fwdS, float* __restrict__ bwdS)
{
    constexpr int NC = L / CK;
    constexpr int LOG2CK = (CK == 64) ? 6 : 7;
    const int tid = blockIdx.x * 256 + threadIdx.x;
    const int m = tid & (ND - 1);
    const int d = (tid >> 4) & (D - 1);
    const int b = tid >> 14;
    const size_t CS = (size_t)D * ND;   // stride between chunks
    const size_t off = (size_t)b * NC * CS + (size_t)d * ND + m;
    float* fb = fwdS + off;
    float* bb = bwdS + off;

    const int idxf = d * ND + m;
    const int idxb = (d + D) * ND + m;
    float qf = 1.f - sigmoid_precise(damp[idxf]) * sigmoid_precise(decay[idxf]);
    float qb = 1.f - sigmoid_precise(damp[idxb]) * sigmoid_precise(decay[idxb]);
#pragma unroll
    for (int s = 0; s < LOG2CK; ++s) { qf *= qf; qb *= qb; }   // q^CK

    float Ef[NC], Eb[NC];
#pragma unroll
    for (int i = 0; i < NC; ++i) Ef[i] = fb[(size_t)i * CS];
#pragma unroll
    for (int i = 0; i < NC; ++i) Eb[i] = bb[(size_t)i * CS];

    float F = 0.f, G = 0.f;
#pragma unroll
    for (int i = 0; i < NC; ++i) {
        fb[(size_t)i * CS] = F;               F = fmaf(qf, F, Ef[i]);
        bb[(size_t)(NC-1-i) * CS] = G;        G = fmaf(qb, G, Eb[NC-1-i]);
    }
}

// ---------------- Phase C: apply (both directions + residual + silu) ---------
// Whole chunk of x in registers; fwd partial results (residual + causal) kept
// in a register tile (no LDS at all). Bwd sweep runs from registers -> the
// only memory ops after the prefetch are the entry-state loads and the final
// coalesced stores.
template<int CK>
__global__ __launch_bounds__(64, 2) void ema_apply_kernel(
    const float* __restrict__ x, const float* __restrict__ damp,
    const float* __restrict__ decay, const float* __restrict__ ema,
    const float* __restrict__ proj, const float* __restrict__ rw,
    const int* __restrict__ mask,
    const float* __restrict__ fwdS, const float* __restrict__ bwdS,
    float* __restrict__ out)
{
    constexpr int NC = L / CK;
    const int lane = threadIdx.x;
    const int d  = blockIdx.x * 64 + lane;
    const int b  = blockIdx.y;
    const int ch = blockIdx.z;
    const int j0 = ch * CK;

    const float* xp = x   + (size_t)j0 * BD + (size_t)b * D + d;
    float*       op = out + (size_t)j0 * BD + (size_t)b * D + d;
    const int*   mp = mask + (size_t)b * L + j0;   // wave-uniform
    const float  w  = rw[d];

    float xv[CK];
#pragma unroll
    for (int u = 0; u < CK; ++u) xv[u] = xp[(size_t)u * BD];

    float q[ND], c[ND], st[ND], tile[CK];

    // ---- forward (causal) sweep ----
    load_qc(damp, decay, ema, proj, d, q, c);
    {
        const float4* s4 = reinterpret_cast<const float4*>(fwdS) + ((size_t)(b * NC + ch) * D + d) * 4;
#pragma unroll
        for (int mg = 0; mg < 4; ++mg) {
            const float4 v = s4[mg];
            st[4*mg+0] = v.x; st[4*mg+1] = v.y; st[4*mg+2] = v.z; st[4*mg+3] = v.w;
        }
    }
#pragma unroll
    for (int u = 0; u < CK; ++u) {
        const float mf  = (float)mp[u];
        const float xmv = xv[u] * mf;
#pragma unroll
        for (int k = 0; k < ND; ++k) st[k] = fmaf(q[k], st[k], xmv);
        float a0 = c[0] * st[0], a1 = c[1] * st[1],
              a2 = c[2] * st[2], a3 = c[3] * st[3];
#pragma unroll
        for (int k = 4; k < ND; k += 4) {
            a0 = fmaf(c[k+0], st[k+0], a0);
            a1 = fmaf(c[k+1], st[k+1], a1);
            a2 = fmaf(c[k+2], st[k+2], a2);
            a3 = fmaf(c[k+3], st[k+3], a3);
        }
        tile[u] = fmaf(xv[u], w, (a0 + a1) + (a2 + a3));
        xv[u] = xmv;   // raw x dead after this point; keep masked value for bwd
    }

    // ---- backward (anti-causal) sweep + combine + silu + coalesced store ----
    load_qc(damp, decay, ema, proj, d + D, q, c);
    {
        const float4* s4 = reinterpret_cast<const float4*>(bwdS) + ((size_t)(b * NC + ch) * D + d) * 4;
#pragma unroll
        for (int mg = 0; mg < 4; ++mg) {
            const float4 v = s4[mg];
            st[4*mg+0] = v.x; st[4*mg+1] = v.y; st[4*mg+2] = v.z; st[4*mg+3] = v.w;
        }
    }
#pragma unroll
    for (int u = CK - 1; u >= 0; --u) {
        const float xmv = xv[u];
#pragma unroll
        for (int k = 0; k < ND; ++k) st[k] = fmaf(q[k], st[k], xmv);
        float a0 = c[0] * st[0], a1 = c[1] * st[1],
              a2 = c[2] * st[2], a3 = c[3] * st[3];
#pragma unroll
        for (int k = 4; k < ND; k += 4) {
            a0 = fmaf(c[k+0], st[k+0], a0);
            a1 = fmaf(c[k+1], st[k+1], a1);
            a2 = fmaf(c[k+2], st[k+2], a2);
            a3 = fmaf(c[k+3], st[k+3], a3);
        }
        const float val = tile[u] + ((a0 + a1) + (a2 + a3));
        op[(size_t)u * BD] = val / (1.0f + expf(-val));
    }
}

// ---------------- Fallback: validated single-pass scans ----------------------
template<int DIR>
__device__ __forceinline__ void ema_scan_body(
    const float* __restrict__ x, const float* __restrict__ damp,
    const float* __restrict__ decay, const float* __restrict__ ema,
    const float* __restrict__ proj, const float* __restrict__ rw,
    const int* __restrict__ mask, float* __restrict__ out)
{
    const int t  = threadIdx.x;
    const int ng = t & 3;
    const int dl = t >> 2;
    const int d  = blockIdx.x * 16 + dl;
    const int b  = blockIdx.y;
    const int row = (DIR == 0) ? d : (d + D);

    float q[4], c[4];
#pragma unroll
    for (int k = 0; k < 4; ++k) {
        const int idx = row * ND + ng * 4 + k;
        const float p  = sigmoid_precise(damp[idx]);
        const float sd = sigmoid_precise(decay[idx]);
        q[k] = 1.0f - p * sd;
        c[k] = p * ema[idx] * proj[idx] * 0.25f;
    }
    const float w = rw[d];
    const float* xp = x + (size_t)b * D + d;
    float*       op = out + (size_t)b * D + d;
    const int*   mp = mask + (size_t)b * L;
    float s0 = 0.f, s1 = 0.f, s2 = 0.f, s3 = 0.f;

    for (int jj = 0; jj < L; jj += 4) {
        float xv[4], mf[4];
#pragma unroll
        for (int u = 0; u < 4; ++u) {
            const int j = (DIR == 0) ? (jj + u) : (L - 1 - (jj + u));
            xv[u] = xp[(size_t)j * BD];
            mf[u] = (float)mp[j];
        }
        float acc[4];
#pragma unroll
        for (int u = 0; u < 4; ++u) {
            const float xm = xv[u] * mf[u];
            s0 = fmaf(q[0], s0, xm);
            s1 = fmaf(q[1], s1, xm);
            s2 = fmaf(q[2], s2, xm);
            s3 = fmaf(q[3], s3, xm);
            acc[u] = fmaf(c[1], s1, c[0] * s0) + fmaf(c[3], s3, c[2] * s2);
        }
#pragma unroll
        for (int u = 0; u < 4; ++u) acc[u] += __shfl_xor(acc[u], 1);
#pragma unroll
        for (int u = 0; u < 4; ++u) acc[u] += __shfl_xor(acc[u], 2);
        if (ng == 0) {
#pragma unroll
            for (int u = 0; u < 4; ++u) {
                const int j = (DIR == 0) ? (jj + u) : (L - 1 - (jj + u));
                const size_t oi = (size_t)j * BD;
                if (DIR == 0) op[oi] = fmaf(xv[u], w, acc[u]);
                else { const float v = op[oi] + acc[u]; op[oi] = v / (1.0f + expf(-v)); }
            }
        }
    }
}

__global__ __launch_bounds__(64) void ema_fwd_kernel(
    const float* __restrict__ x, const float* __restrict__ damp,
    const float* __restrict__ decay, const float* __restrict__ ema,
    const float* __restrict__ proj, const float* __restrict__ rw,
    const int* __restrict__ mask, float* __restrict__ out)
{ ema_scan_body<0>(x, damp, decay, ema, proj, rw, mask, out); }

__global__ __launch_bounds__(64) void ema_bwd_kernel(
    const float* __restrict__ x, const float* __restrict__ damp,
    const float* __restrict__ decay, const float* __restrict__ ema,
    const float* __restrict__ proj, const float* __restrict__ rw,
    const int* __restrict__ mask, float* __restrict__ out)
{ ema_scan_body<1>(x, damp, decay, ema, proj, rw, mask, out); }

// ---------------- driver -----------------------------------------------------
template<int CK>
static void launch_chunked(const float* x, const float* damp, const float* decay,
                           const float* ema, const float* proj, const float* rw,
                           const int* mask, float* out, float* ws, hipStream_t stream) {
    constexpr int NC = L / CK;
    float* fwdS = ws;
    float* bwdS = fwdS + (size_t)B * NC * D * ND;
    dim3 blk(64);
    dim3 g(D / 64, B, NC);
    ema_summary_kernel<CK><<<g, blk, 0, stream>>>(x, damp, decay, mask, fwdS, bwdS);
    ema_prefix_kernel<CK><<<dim3((B * D * ND) / 256), dim3(256), 0, stream>>>(damp, decay, fwdS, bwdS);
    ema_apply_kernel<CK><<<g, blk, 0, stream>>>(x, damp, decay, ema, proj, rw, mask,
                                                fwdS, bwdS, out);
}

extern "C" void kernel_launch(void* const* d_in, const int* in_sizes, int n_in,
                              void* d_out, int out_size, void* d_ws, size_t ws_size,
                              hipStream_t stream) {
    (void)in_sizes; (void)n_in; (void)out_size;
    const float* x     = (const float*)d_in[0];
    const float* damp  = (const float*)d_in[1];
    const float* decay = (const float*)d_in[2];
    const float* ema   = (const float*)d_in[3];
    const float* proj  = (const float*)d_in[4];
    const float* rw    = (const float*)d_in[5];
    const int*   mask  = (const int*)d_in[6];
    float* out = (float*)d_out;

    const size_t need64 = (size_t)2 * B * (L / 64) * D * ND * sizeof(float);  // 33.6 MB

    if (ws_size >= need64) {
        launch_chunked<64>(x, damp, decay, ema, proj, rw, mask, out, (float*)d_ws, stream);
    } else {
        dim3 grid(D / 16, B);
        dim3 block(64);
        ema_fwd_kernel<<<grid, block, 0, stream>>>(x, damp, decay, ema, proj, rw, mask, out);
        ema_bwd_kernel<<<grid, block, 0, stream>>>(x, damp, decay, ema, proj, rw, mask, out);
    }
}